// Round 6
// baseline (149.217 us; speedup 1.0000x reference)
//
#include <hip/hip_runtime.h>

// Problem constants
#define NPTS   3000
#define MPTS   3000
#define KNODES 6000
#define HEADS  4
#define FDIM   256      // HEADS*HID
#define OUTC   2
#define R2     0.0025f
#define NSLOPE 0.2f
#define MAXNBR 64
#define RPB    8        // rows per K1 block -> 750 blocks (~3/CU)

// ---------------- workspace layout (floats) ----------------
#define OFF_ES2  0
#define OFF_ED2  24000
#define OFF_H2   48000        // 6000*256
#define OFF_END  1584000      // floats; int region starts at byte 4*OFF_END

__device__ __forceinline__ float4 fma4(float s, float4 w, float4 a) {
    a.x = fmaf(s, w.x, a.x); a.y = fmaf(s, w.y, a.y);
    a.z = fmaf(s, w.z, a.z); a.w = fmaf(s, w.w, a.w);
    return a;
}

// K1: per block of 8 rows, fully block-local up to h2:
//  A) radius scan (exact fp32 gram-trick ops -> bit-identical mask)
//  B) layer-1 softmax-agg, recomputing h1[j]/es1[j] on the fly (h1 is a
//     rank-3 transform: 3 fmaf/thread) -> x rows in LDS only
//  C) gemm2 (x@W2) + layer-2 scores -> h2, es2, ed2 to global
__global__ __launch_bounds__(256) void k_l1(
        const float* __restrict__ pos, const float* __restrict__ pnm,
        const float* __restrict__ W1, const float* __restrict__ as1,
        const float* __restrict__ ad1, const float* __restrict__ b1,
        const float* __restrict__ W2, const float* __restrict__ as2,
        const float* __restrict__ ad2,
        float* __restrict__ h2, float* __restrict__ es2, float* __restrict__ ed2,
        int* __restrict__ cnt, int* __restrict__ idx) {
    __shared__ int s_cnt[RPB];
    __shared__ int s_idx[RPB][MAXNBR];
    __shared__ __align__(16) float xs[RPB][FDIM];
    const int t = threadIdx.x;
    const int lane = t & 63;
    const int i0 = blockIdx.x * RPB;

    // ---- Phase A: neighbor scan ----
    if (t < RPB) s_cnt[t] = 0;
    __syncthreads();
    // 3000 % RPB == 0 -> a block's rows never straddle pos/pnm
    const float* base = (i0 < NPTS) ? pos : pnm;
    const int ib = (i0 < NPTS) ? i0 : i0 - NPTS;
    float xi[RPB], yi[RPB], zi[RPB], si[RPB];
#pragma unroll
    for (int r = 0; r < RPB; ++r) {
        float x = base[ib + r], y = base[NPTS + ib + r], z = base[2 * NPTS + ib + r];
        xi[r] = x; yi[r] = y; zi[r] = z;
        si[r] = __fadd_rn(__fadd_rn(__fmul_rn(x, x), __fmul_rn(y, y)), __fmul_rn(z, z));
    }
    for (int j = t; j < KNODES; j += 256) {
        float xj, yj, zj;
        if (j < NPTS) { xj = pos[j]; yj = pos[NPTS + j]; zj = pos[2 * NPTS + j]; }
        else { int q = j - NPTS; xj = pnm[q]; yj = pnm[MPTS + q]; zj = pnm[2 * MPTS + q]; }
        float sj = __fadd_rn(__fadd_rn(__fmul_rn(xj, xj), __fmul_rn(yj, yj)),
                             __fmul_rn(zj, zj));
#pragma unroll
        for (int r = 0; r < RPB; ++r) {
            float dot = __fadd_rn(__fadd_rn(__fmul_rn(xi[r], xj), __fmul_rn(yi[r], yj)),
                                  __fmul_rn(zi[r], zj));
            float d2 = __fsub_rn(__fadd_rn(si[r], sj), __fmul_rn(2.0f, dot));
            if (d2 < R2) {
                int p = atomicAdd(&s_cnt[r], 1);
                if (p < MAXNBR) s_idx[r][p] = j;
            }
        }
    }
    __syncthreads();
    if (t < RPB) cnt[i0 + t] = min(s_cnt[t], MAXNBR);
#pragma unroll
    for (int r = 0; r < RPB; ++r) {
        int c = min(s_cnt[r], MAXNBR);
        if (t < c) idx[(i0 + r) * MAXNBR + t] = s_idx[r][t];
    }

    // ---- Phase B: layer-1 agg with on-the-fly recompute ----
    const float w1a = W1[t], w1b = W1[FDIM + t], w1c = W1[2 * FDIM + t];
    const float asv = as1[t], adv = ad1[t], b1v = b1[t];
    for (int r = 0; r < RPB; ++r) {
        int c = min(s_cnt[r], MAXNBR);
        // own-row dst score (per head = per wave), all lanes via xor-reduce
        float h1i = fmaf(xi[r], w1a, fmaf(yi[r], w1b, zi[r] * w1c));
        float dsum = h1i * adv;
#pragma unroll
        for (int off = 32; off; off >>= 1) dsum += __shfl_xor(dsum, off, 64);
        // pass 1: e[jl] kept in lane jl's register
        float e_keep = -1e30f;
        for (int jl = 0; jl < c; ++jl) {
            int j = s_idx[r][jl];
            float xj, yj, zj;
            if (j < NPTS) { xj = pos[j]; yj = pos[NPTS + j]; zj = pos[2 * NPTS + j]; }
            else { int q = j - NPTS; xj = pnm[q]; yj = pnm[MPTS + q]; zj = pnm[2 * MPTS + q]; }
            float h1j = fmaf(xj, w1a, fmaf(yj, w1b, zj * w1c));
            float ssc = h1j * asv;
#pragma unroll
            for (int off = 32; off; off >>= 1) ssc += __shfl_xor(ssc, off, 64);
            float e = dsum + ssc;
            e = (e >= 0.f) ? e : NSLOPE * e;
            e_keep = (lane == jl) ? e : e_keep;
        }
        float mv = (lane < c) ? e_keep : -1e30f;
#pragma unroll
        for (int off = 32; off; off >>= 1) mv = fmaxf(mv, __shfl_xor(mv, off, 64));
        // pass 2: softmax-weighted aggregate (recompute h1j: 3 fmaf)
        float ssum = 0.f, acc = 0.f;
        for (int jl = 0; jl < c; ++jl) {
            int j = s_idx[r][jl];
            float xj, yj, zj;
            if (j < NPTS) { xj = pos[j]; yj = pos[NPTS + j]; zj = pos[2 * NPTS + j]; }
            else { int q = j - NPTS; xj = pnm[q]; yj = pnm[MPTS + q]; zj = pnm[2 * MPTS + q]; }
            float h1j = fmaf(xj, w1a, fmaf(yj, w1b, zj * w1c));
            float p = __expf(__shfl(e_keep, jl, 64) - mv);
            ssum += p;
            acc = fmaf(p, h1j, acc);
        }
        xs[r][t] = fmaxf(acc / ssum + b1v, 0.f);
    }
    __syncthreads();

    // ---- Phase C: gemm2 (2 rows/wave) + layer-2 scores ----
    {
        const int wv = t >> 6;
        const float4* W4  = (const float4*)W2;
        const float4* xr0 = (const float4*)xs[2 * wv];
        const float4* xr1 = (const float4*)xs[2 * wv + 1];
        float4 a0 = {0.f, 0.f, 0.f, 0.f}, a1 = a0;
        for (int k4 = 0; k4 < FDIM / 4; ++k4) {
            float4 xa = xr0[k4], xb = xr1[k4];            // LDS broadcast
            float4 q0 = W4[(4 * k4 + 0) * 64 + lane];     // coalesced dwordx4
            float4 q1 = W4[(4 * k4 + 1) * 64 + lane];
            float4 q2 = W4[(4 * k4 + 2) * 64 + lane];
            float4 q3 = W4[(4 * k4 + 3) * 64 + lane];
            a0 = fma4(xa.x, q0, fma4(xa.y, q1, fma4(xa.z, q2, fma4(xa.w, q3, a0))));
            a1 = fma4(xb.x, q0, fma4(xb.y, q1, fma4(xb.z, q2, fma4(xb.w, q3, a1))));
        }
        const float4 as4 = ((const float4*)as2)[lane];
        const float4 ad4 = ((const float4*)ad2)[lane];
        const int head = lane >> 4;
        float4 accs[2] = {a0, a1};
#pragma unroll
        for (int r = 0; r < 2; ++r) {
            int row = i0 + 2 * wv + r;
            ((float4*)(h2 + (size_t)row * FDIM))[lane] = accs[r];
            float4 a = accs[r];
            float s = fmaf(a.x, as4.x, fmaf(a.y, as4.y, fmaf(a.z, as4.z, a.w * as4.w)));
            float d = fmaf(a.x, ad4.x, fmaf(a.y, ad4.y, fmaf(a.z, ad4.z, a.w * ad4.w)));
#pragma unroll
            for (int off = 8; off; off >>= 1) {     // sums lanes [g*16, g*16+16)
                s += __shfl_down(s, off, 64);
                d += __shfl_down(d, off, 64);
            }
            if ((lane & 15) == 0) {
                es2[row * HEADS + head] = s;
                ed2[row * HEADS + head] = d;
            }
        }
    }
}

// K2: layer-2 aggregate + bias + relu + fc, output nodes only.
__global__ void k_agg2fc(const float* __restrict__ h, const float* __restrict__ es,
                         const float* __restrict__ ed, const int* __restrict__ cnt,
                         const int* __restrict__ idx, const float* __restrict__ bias,
                         const float* __restrict__ fw, const float* __restrict__ fb,
                         float* __restrict__ out) {
    __shared__ int   s_idx[MAXNBR];
    __shared__ float s_e[MAXNBR * HEADS];
    __shared__ float s_ed[HEADS];
    __shared__ float s_red[8];
    int q = blockIdx.x;
    int i = MPTS + q;
    int t = threadIdx.x;
    int c = cnt[i];
    if (t < c) s_idx[t] = idx[i * MAXNBR + t];
    if (t < HEADS) s_ed[t] = ed[i * HEADS + t];
    __syncthreads();
    if (t < c * HEADS) {
        int jl = t >> 2, hh = t & 3;
        float e = s_ed[hh] + es[s_idx[jl] * HEADS + hh];
        e = (e >= 0.f) ? e : NSLOPE * e;
        s_e[jl * HEADS + hh] = e;
    }
    __syncthreads();
    int hh = t >> 6;
    float m = -1e30f;
    for (int jl = 0; jl < c; ++jl) m = fmaxf(m, s_e[jl * HEADS + hh]);
    float ssum = 0.f, acc = 0.f;
    for (int jl = 0; jl < c; ++jl) {
        float p = __expf(s_e[jl * HEADS + hh] - m);
        ssum += p;
        acc = fmaf(p, h[s_idx[jl] * FDIM + t], acc);
    }
    float v = fmaxf(acc / ssum + bias[t], 0.f);
    float p0 = v * fw[t * OUTC + 0];
    float p1 = v * fw[t * OUTC + 1];
    for (int off = 32; off; off >>= 1) {
        p0 += __shfl_down(p0, off, 64);
        p1 += __shfl_down(p1, off, 64);
    }
    if ((t & 63) == 0) {
        s_red[(t >> 6) * 2 + 0] = p0;
        s_red[(t >> 6) * 2 + 1] = p1;
    }
    __syncthreads();
    if (t == 0) {
        out[q * OUTC + 0] = s_red[0] + s_red[2] + s_red[4] + s_red[6] + fb[0];
        out[q * OUTC + 1] = s_red[1] + s_red[3] + s_red[5] + s_red[7] + fb[1];
    }
}

extern "C" void kernel_launch(void* const* d_in, const int* in_sizes, int n_in,
                              void* d_out, int out_size, void* d_ws, size_t ws_size,
                              hipStream_t stream) {
    const float* pos   = (const float*)d_in[0];
    const float* pnm   = (const float*)d_in[1];
    const float* W1    = (const float*)d_in[2];
    const float* asrc1 = (const float*)d_in[3];
    const float* adst1 = (const float*)d_in[4];
    const float* b1    = (const float*)d_in[5];
    const float* W2    = (const float*)d_in[6];
    const float* asrc2 = (const float*)d_in[7];
    const float* adst2 = (const float*)d_in[8];
    const float* b2    = (const float*)d_in[9];
    const float* fcw   = (const float*)d_in[10];
    const float* fcb   = (const float*)d_in[11];
    float* out = (float*)d_out;

    float* w    = (float*)d_ws;
    float* es2  = w + OFF_ES2;
    float* ed2  = w + OFF_ED2;
    float* h2   = w + OFF_H2;
    int* nbr_cnt = (int*)((char*)d_ws + (size_t)4 * OFF_END);
    int* nbr_idx = nbr_cnt + KNODES;

    // K1: nbr + layer-1 (recompute trick) + gemm2 + scores2
    k_l1<<<KNODES / RPB, 256, 0, stream>>>(pos, pnm, W1, asrc1, adst1, b1,
                                           W2, asrc2, adst2, h2, es2, ed2,
                                           nbr_cnt, nbr_idx);
    // K2: layer-2 aggregate + fc
    k_agg2fc<<<MPTS, FDIM, 0, stream>>>(h2, es2, ed2, nbr_cnt, nbr_idx, b2,
                                        fcw, fcb, out);
}